// Round 17
// baseline (280.964 us; speedup 1.0000x reference)
//
#include <hip/hip_runtime.h>
#include <hip/hip_bf16.h>

#define CC 192

typedef __attribute__((ext_vector_type(8))) short bf16x8;
typedef __attribute__((ext_vector_type(4))) float f32x4;

// RNE float->bf16 via the compiler's native cast (lowers to v_cvt_pk_bf16_f32-class ops;
// manual bit-twiddle RNE costs ~3 VALU ops per value).
__device__ __forceinline__ unsigned short f2bf(float f) {
    __hip_bfloat16 h = __float2bfloat16(f);
    unsigned short u;
    __builtin_memcpy(&u, &h, 2);
    return u;
}

__device__ __forceinline__ float bf2f(unsigned short u) {
    return __uint_as_float(((unsigned int)u) << 16);
}

// 2^x via native v_exp_f32 (single VALU op).
__device__ __forceinline__ float fast_exp2(float x) {
#if __has_builtin(__builtin_amdgcn_exp2f)
    return __builtin_amdgcn_exp2f(x);
#else
    return __expf(0.69314718055994531f * x);
#endif
}

__device__ __forceinline__ f32x4 mfma16(bf16x8 a, bf16x8 b, f32x4 c) {
    return __builtin_amdgcn_mfma_f32_16x16x32_bf16(a, b, c, 0, 0, 0);
}

// Merged prep: 4 weight transposes (f32 [K][N] -> bf16 [N][K]) + 4-class masked bias table.
// Bias table premultiplied by 1/ln2 so softmax uses native exp2 (no per-score mul).
__global__ void k_prep(const float* __restrict__ qkv_w, const float* __restrict__ proj_w,
                       const float* __restrict__ w1, const float* __restrict__ w2,
                       const float* __restrict__ relTab,
                       unsigned short* __restrict__ qkvT, unsigned short* __restrict__ projT,
                       unsigned short* __restrict__ w1T, unsigned short* __restrict__ w2T,
                       unsigned short* __restrict__ biasT4) {
    int idx = blockIdx.x * blockDim.x + threadIdx.x;
    if (idx < 110592) { int n = idx / 192, k = idx % 192; qkvT[idx] = f2bf(qkv_w[k * 576 + n]); return; }
    idx -= 110592;
    if (idx < 36864)  { int n = idx / 192, k = idx % 192; projT[idx] = f2bf(proj_w[k * 192 + n]); return; }
    idx -= 36864;
    if (idx < 73728)  { int n = idx / 192, k = idx % 192; w1T[idx] = f2bf(w1[k * 384 + n]); return; }
    idx -= 73728;
    if (idx < 73728)  { int n = idx / 384, k = idx % 384; w2T[idx] = f2bf(w2[k * 192 + n]); return; }
    idx -= 73728;
    if (idx < 98304) {   // [cls][h][i][j]: cls = (edgeH?2:0)+(edgeW?1:0); mask pre-added; x 1/ln2
        const int cls = idx / 24576, rem = idx % 24576;
        const int h = rem >> 12, i = (rem >> 6) & 63, j = rem & 63;
        const int yi = i >> 3, xi = i & 7, yj = j >> 3, xj = j & 7;
        const int rel = (yi - yj + 7) * 15 + (xi - xj + 7);
        float v = relTab[rel * 6 + h];
        const int bH = cls >> 1, bW = cls & 1;
        const int idi = (bH ? (yi >= 4 ? 2 : 1) : 0) * 3 + (bW ? (xi >= 4 ? 2 : 1) : 0);
        const int idj = (bH ? (yj >= 4 ? 2 : 1) : 0) * 3 + (bW ? (xj >= 4 ? 2 : 1) : 0);
        if (idi != idj) v -= 100.f;   // exp2(-144+O(1)) flushes to 0: exact mask semantics
        biasT4[idx] = f2bf(v * 1.4426950408889634f);
    }
}

// FUSED Swin block: one window per block (2048 blocks), 12 waves (768 threads).
// R16-proven structure (277 us, zero spill). This round: compiler bf16 casts + manual
// cross-barrier B-fragment prefetch (compiler cannot hoist global loads past barriers;
// the barrier's vmcnt(0) drain guarantees prefetched frags are ready after it).
// LDS: rA [0,24K): A -> VT -> AO -> A2 | rQ [24K,48K): Q -> P lo -> h-bf16 |
//      rK [48K,72K): K -> P hi -> G-half (MLP two-pass)
__global__ __launch_bounds__(768, 3) void k_fused(
    const float* __restrict__ x,
    const float* __restrict__ n1g, const float* __restrict__ n1b,
    const unsigned short* __restrict__ qkvT, const float* __restrict__ qkv_b,
    const unsigned short* __restrict__ projT, const float* __restrict__ proj_b,
    const unsigned short* __restrict__ biasT4,
    const float* __restrict__ n2g, const float* __restrict__ n2b,
    const unsigned short* __restrict__ w1T, const float* __restrict__ b1,
    const unsigned short* __restrict__ w2T, const float* __restrict__ b2,
    float* __restrict__ out)
{
    __shared__ __align__(16) char smem[73728];
    __shared__ int sOpos[64];
    char* const rA = smem;
    char* const rQ = smem + 24576;
    char* const rK = smem + 49152;

    const int tid = threadIdx.x;
    const int wid = blockIdx.x;
    const int b = wid >> 6;
    const int win = wid & 63;
    const int wh = win >> 3, ww = win & 7;
    const int lane = tid & 63;
    const int wave = tid >> 6;
    const int lhi = lane >> 4, llo = lane & 15;

    // ---------- Phase 1: LN1 + shifted window gather (512 threads, 8/token) ----------
    if (tid < 512) {
        const int tok = tid >> 3;
        const int ch0 = (tid & 7) * 24;
        const int yi = tok >> 3, xi = tok & 7;
        const int oy = (wh * 8 + yi + 4) & 63;
        const int ox = (ww * 8 + xi + 4) & 63;
        const int base = ((b * 64 + oy) * 64 + ox) * CC;
        if ((tid & 7) == 0) sOpos[tok] = base;
        float v[24];
        float s = 0.f, ss = 0.f;
        #pragma unroll
        for (int i = 0; i < 6; ++i) {
            const float4 f = *(const float4*)(x + base + ch0 + i * 4);
            v[i*4+0]=f.x; v[i*4+1]=f.y; v[i*4+2]=f.z; v[i*4+3]=f.w;
            s  += f.x + f.y + f.z + f.w;
            ss += f.x*f.x + f.y*f.y + f.z*f.z + f.w*f.w;
        }
        s  += __shfl_xor(s, 1);  s  += __shfl_xor(s, 2);  s  += __shfl_xor(s, 4);
        ss += __shfl_xor(ss, 1); ss += __shfl_xor(ss, 2); ss += __shfl_xor(ss, 4);
        const float mean = s * (1.f / 192.f);
        const float rstd = rsqrtf(ss * (1.f / 192.f) - mean * mean + 1e-5f);
        char* aBase = rA + tok * 384;
        const int sw = (tok & 7) << 4;
        #pragma unroll
        for (int i = 0; i < 12; ++i) {
            const int c = ch0 + i * 2;
            const float a0 = (v[i*2+0] - mean) * rstd * n1g[c]   + n1b[c];
            const float a1 = (v[i*2+1] - mean) * rstd * n1g[c+1] + n1b[c+1];
            *(unsigned int*)(aBase + ((c * 2) ^ sw)) =
                (unsigned int)f2bf(a0) | ((unsigned int)f2bf(a1) << 16);
        }
    }
    // prefetch QKV ks=0 B-fragments (ready after bar1's vmcnt drain; hides L2 latency)
    bf16x8 pfQKV[3];
    #pragma unroll
    for (int n = 0; n < 3; ++n)
        pfQKV[n] = *(const bf16x8*)(qkvT + (wave * 48 + n * 16 + llo) * 192 + lhi * 8);
    __syncthreads();   // bar1: A ready

    // ---------- Phase 2: QKV GEMM, wave w -> cols [48w, 48w+48) ----------
    {
        const int cbase = wave * 48;
        f32x4 acc[4][3] = {};
        #pragma unroll
        for (int ks = 0; ks < 6; ++ks) {
            bf16x8 af[4];
            const int kbyte = ks * 64 + lhi * 16;
            #pragma unroll
            for (int m = 0; m < 4; ++m) {
                const int row = m * 16 + llo;
                af[m] = *(const bf16x8*)(rA + row * 384 + (kbyte ^ ((row & 7) << 4)));
            }
            #pragma unroll
            for (int n = 0; n < 3; ++n) {
                const bf16x8 bfr = (ks == 0) ? pfQKV[n]
                    : *(const bf16x8*)(qkvT + (cbase + n * 16 + llo) * 192 + ks * 32 + lhi * 8);
                #pragma unroll
                for (int m = 0; m < 4; ++m) acc[m][n] = mfma16(af[m], bfr, acc[m][n]);
            }
        }
        __syncthreads();   // bar2: A fully consumed; rA region free for VT
        // epilogue: +bias, scatter to Q/K/VT LDS (SCALE*1/ln2 folded into Q for exp2 softmax)
        #pragma unroll
        for (int n = 0; n < 3; ++n) {
            const int c0 = cbase + n * 16;
            const int which = c0 / 192;
            const int rem = c0 - which * 192;
            const int h = rem >> 5;
            const int d = (rem & 31) + llo;
            const float bia = qkv_b[c0 + llo];
            #pragma unroll
            for (int m = 0; m < 4; ++m) {
                #pragma unroll
                for (int r = 0; r < 4; ++r) {
                    const int row = m * 16 + lhi * 4 + r;
                    if (which == 0)
                        *(unsigned short*)(rQ + h * 4096 + row * 64 + ((2 * d) ^ ((row & 3) << 4)))
                            = f2bf((acc[m][n][r] + bia) * 0.2550510257216822f);
                    else if (which == 1)
                        *(unsigned short*)(rK + h * 4096 + row * 64 + ((2 * d) ^ ((row & 3) << 4)))
                            = f2bf(acc[m][n][r] + bia);
                    else
                        *(unsigned short*)(rA + h * 4096 + d * 128 + ((2 * row) ^ ((d & 7) << 4)))
                            = f2bf(acc[m][n][r] + bia);
                }
            }
        }
    }
    __syncthreads();   // bar3: Q/K/VT visible

    // ---------- Phase 3: attention (head = wave>>1, row-half = wave&1) ----------
    const int h = wave >> 1;
    const int mh = wave & 1;
    f32x4 pacc[2][2] = {};
    float rinv[2][4];
    bf16x8 bfrP[6];   // proj B-panel prefetch (used after bar6)
    {
        bf16x8 qf[2], kf[4];
        #pragma unroll
        for (int m = 0; m < 2; ++m) {
            const int t = (mh * 2 + m) * 16 + llo;
            qf[m] = *(const bf16x8*)(rQ + h * 4096 + t * 64 + ((lhi * 16) ^ ((t & 3) << 4)));
        }
        #pragma unroll
        for (int n = 0; n < 4; ++n) {
            const int t = n * 16 + llo;
            kf[n] = *(const bf16x8*)(rK + h * 4096 + t * 64 + ((lhi * 16) ^ ((t & 3) << 4)));
        }
        // prefetch the full proj B-panel during attention (hidden under QK^T/softmax/PV)
        #pragma unroll
        for (int ks = 0; ks < 6; ++ks)
            bfrP[ks] = *(const bf16x8*)(projT + (wave * 16 + llo) * 192 + ks * 32 + lhi * 8);
        __syncthreads();   // bar4: Q/K in registers everywhere; rQ+rK free for P

        f32x4 sacc[2][4] = {};
        #pragma unroll
        for (int m = 0; m < 2; ++m)
            #pragma unroll
            for (int n = 0; n < 4; ++n)
                sacc[m][n] = mfma16(qf[m], kf[n], sacc[m][n]);

        // 4-class premasked, pre-1/ln2 bias table: softmax on native exp2, no-max
        const int cls = ((wh == 7) ? 2 : 0) + ((ww == 7) ? 1 : 0);
        const unsigned short* bT = biasT4 + cls * 24576 + h * 4096;
        #pragma unroll
        for (int m = 0; m < 2; ++m) {
            #pragma unroll
            for (int r = 0; r < 4; ++r) {
                const int i = (mh * 2 + m) * 16 + lhi * 4 + r;
                float sum = 0.f;
                unsigned short pb[4];
                #pragma unroll
                for (int n = 0; n < 4; ++n) {
                    const int j = n * 16 + llo;
                    const float e = fast_exp2(sacc[m][n][r] + bf2f(bT[i * 64 + j]));
                    sum += e;
                    pb[n] = f2bf(e);
                }
                sum += __shfl_xor(sum, 1);
                sum += __shfl_xor(sum, 2);
                sum += __shfl_xor(sum, 4);
                sum += __shfl_xor(sum, 8);
                rinv[m][r] = 1.f / sum;
                #pragma unroll
                for (int n = 0; n < 4; ++n) {
                    const int j = n * 16 + llo;
                    *(unsigned short*)(rQ + h * 8192 + i * 128 + ((2 * j) ^ ((i & 7) << 4))) = pb[n];
                }
            }
        }
        // P is wave-private (own 32 rows) -> no barrier before PV.
        #pragma unroll
        for (int ks = 0; ks < 2; ++ks) {
            bf16x8 pf[2];
            #pragma unroll
            for (int m = 0; m < 2; ++m) {
                const int t = (mh * 2 + m) * 16 + llo;
                pf[m] = *(const bf16x8*)(rQ + h * 8192 + t * 128 + ((ks * 64 + lhi * 16) ^ ((t & 7) << 4)));
            }
            #pragma unroll
            for (int n = 0; n < 2; ++n) {
                const int d = n * 16 + llo;
                const bf16x8 vf = *(const bf16x8*)(rA + h * 4096 + d * 128 + ((ks * 64 + lhi * 16) ^ ((d & 7) << 4)));
                #pragma unroll
                for (int m = 0; m < 2; ++m) pacc[m][n] = mfma16(pf[m], vf, pacc[m][n]);
            }
        }
    }
    __syncthreads();   // bar5: all VT/P reads done; rA free for AO
    {
        #pragma unroll
        for (int m = 0; m < 2; ++m) {
            #pragma unroll
            for (int n = 0; n < 2; ++n) {
                const int c = h * 32 + n * 16 + llo;
                #pragma unroll
                for (int r = 0; r < 4; ++r) {
                    const int i = (mh * 2 + m) * 16 + lhi * 4 + r;
                    *(unsigned short*)(rA + i * 384 + ((c * 2) ^ ((i & 7) << 4)))
                        = f2bf(pacc[m][n][r] * rinv[m][r]);
                }
            }
        }
    }
    __syncthreads();   // bar6: AO ready

    // ---------- Phase 4: proj GEMM + residual -> h (bf16) kept in LDS at rQ ----------
    bf16x8 bfrW1[6];   // w1 half-0 B-panel prefetch (used after bar8)
    {
        const int cbase = wave * 16;
        f32x4 acc[4] = {};
        #pragma unroll
        for (int ks = 0; ks < 6; ++ks) {
            bf16x8 af[4];
            const int kbyte = ks * 64 + lhi * 16;
            #pragma unroll
            for (int m = 0; m < 4; ++m) {
                const int row = m * 16 + llo;
                af[m] = *(const bf16x8*)(rA + row * 384 + (kbyte ^ ((row & 7) << 4)));
            }
            #pragma unroll
            for (int m = 0; m < 4; ++m) acc[m] = mfma16(af[m], bfrP[ks], acc[m]);
        }
        // prefetch w1 half-0 panel during proj epilogue (hidden under LN2 + barriers)
        #pragma unroll
        for (int ks = 0; ks < 6; ++ks)
            bfrW1[ks] = *(const bf16x8*)(w1T + (wave * 16 + llo) * 192 + ks * 32 + lhi * 8);
        const int c = cbase + llo;
        const float pb = proj_b[c];
        #pragma unroll
        for (int m = 0; m < 4; ++m) {
            #pragma unroll
            for (int r = 0; r < 4; ++r) {
                const int i = m * 16 + lhi * 4 + r;
                const float hv = x[sOpos[i] + c] + acc[m][r] + pb;
                *(unsigned short*)(rQ + i * 384 + ((2 * c) ^ ((i & 7) << 4))) = f2bf(hv);
            }
        }
    }
    __syncthreads();   // bar7: h-bf16 visible in rQ

    // ---------- Phase 5: LN2 from LDS h -> A2 at rA ----------
    if (tid < 512) {
        const int tok = tid >> 3;
        const int ch0 = (tid & 7) * 24;
        const int sw = (tok & 7) << 4;
        float v[24]; float s = 0.f, ss = 0.f;
        #pragma unroll
        for (int i = 0; i < 12; ++i) {
            const int c = ch0 + i * 2;
            const unsigned uu = *(const unsigned*)(rQ + tok * 384 + ((2 * c) ^ sw));
            const float a0 = bf2f((unsigned short)uu);
            const float a1 = bf2f((unsigned short)(uu >> 16));
            v[2*i] = a0; v[2*i+1] = a1;
            s += a0 + a1;
            ss += a0 * a0 + a1 * a1;
        }
        s  += __shfl_xor(s, 1);  s  += __shfl_xor(s, 2);  s  += __shfl_xor(s, 4);
        ss += __shfl_xor(ss, 1); ss += __shfl_xor(ss, 2); ss += __shfl_xor(ss, 4);
        const float mean = s * (1.f / 192.f);
        const float rstd = rsqrtf(ss * (1.f / 192.f) - mean * mean + 1e-5f);
        char* aBase = rA + tok * 384;
        #pragma unroll
        for (int i = 0; i < 12; ++i) {
            const int c = ch0 + i * 2;
            const float a0 = (v[i*2]   - mean) * rstd * n2g[c]   + n2b[c];
            const float a1 = (v[i*2+1] - mean) * rstd * n2g[c+1] + n2b[c+1];
            *(unsigned int*)(aBase + ((c * 2) ^ sw)) =
                (unsigned int)f2bf(a0) | ((unsigned int)f2bf(a1) << 16);
        }
    }
    __syncthreads();   // bar8: A2 ready; rK free for G-half

    // ---------- Phase 6: MLP in two hidden halves; G-half [64][192] at rK ----------
    f32x4 accM[4] = {};
    #pragma unroll
    for (int hh = 0; hh < 2; ++hh) {
        // GEMM1 half: cols [hh*192 + 16w, +16), native-exp2 GELU -> G-half
        {
            f32x4 a1[4] = {};
            #pragma unroll
            for (int ks = 0; ks < 6; ++ks) {
                bf16x8 af[4];
                const int kbyte = ks * 64 + lhi * 16;
                #pragma unroll
                for (int m = 0; m < 4; ++m) {
                    const int row = m * 16 + llo;
                    af[m] = *(const bf16x8*)(rA + row * 384 + (kbyte ^ ((row & 7) << 4)));
                }
                const bf16x8 bfr = (hh == 0) ? bfrW1[ks]
                    : *(const bf16x8*)(w1T + (192 + wave * 16 + llo) * 192 + ks * 32 + lhi * 8);
                #pragma unroll
                for (int m = 0; m < 4; ++m) a1[m] = mfma16(af[m], bfr, a1[m]);
            }
            const int cl = wave * 16 + llo;
            const float bb = b1[hh * 192 + cl];
            #pragma unroll
            for (int m = 0; m < 4; ++m) {
                #pragma unroll
                for (int r = 0; r < 4; ++r) {
                    const int i = m * 16 + lhi * 4 + r;
                    const float u = a1[m][r] + bb;
                    // gelu_tanh == u / (1 + 2^{-(2k/ln2)(u+0.044715u^3)})
                    const float xx = 2.3022211096534824f * (u + 0.044715f * u * u * u);
                    const float g = u / (1.f + fast_exp2(-xx));
                    *(unsigned short*)(rK + i * 384 + ((2 * cl) ^ ((i & 7) << 4))) = f2bf(g);
                }
            }
        }
        __syncthreads();   // G-half ready
        // GEMM2 partial: K = [hh*192,+192), wave -> out cols [16w,+16)
        {
            #pragma unroll
            for (int ks = 0; ks < 6; ++ks) {
                bf16x8 af[4];
                const int kbyte = ks * 64 + lhi * 16;
                #pragma unroll
                for (int m = 0; m < 4; ++m) {
                    const int row = m * 16 + llo;
                    af[m] = *(const bf16x8*)(rK + row * 384 + (kbyte ^ ((row & 7) << 4)));
                }
                const bf16x8 bfr = *(const bf16x8*)(w2T + (wave * 16 + llo) * 384 + hh * 192 + ks * 32 + lhi * 8);
                #pragma unroll
                for (int m = 0; m < 4; ++m) accM[m] = mfma16(af[m], bfr, accM[m]);
            }
        }
        if (hh == 0) __syncthreads();   // G-half0 consumed; final barrier dropped
    }
    // ---------- final: out = h + mlp (single global write) ----------
    {
        const int c = wave * 16 + llo;
        const float bb = b2[c];
        #pragma unroll
        for (int m = 0; m < 4; ++m) {
            #pragma unroll
            for (int r = 0; r < 4; ++r) {
                const int i = m * 16 + lhi * 4 + r;
                const float hv = bf2f(*(const unsigned short*)(rQ + i * 384 + ((2 * c) ^ ((i & 7) << 4))));
                out[sOpos[i] + c] = hv + accM[m][r] + bb;
            }
        }
    }
}

extern "C" void kernel_launch(void* const* d_in, const int* in_sizes, int n_in,
                              void* d_out, int out_size, void* d_ws, size_t ws_size,
                              hipStream_t stream)
{
    const float* x      = (const float*)d_in[0];
    const float* n1g    = (const float*)d_in[1];
    const float* n1b    = (const float*)d_in[2];
    const float* qkv_w  = (const float*)d_in[3];
    const float* qkv_b  = (const float*)d_in[4];
    const float* proj_w = (const float*)d_in[5];
    const float* proj_b = (const float*)d_in[6];
    const float* relTab = (const float*)d_in[7];
    const float* n2g    = (const float*)d_in[8];
    const float* n2b    = (const float*)d_in[9];
    const float* w1     = (const float*)d_in[10];
    const float* b1     = (const float*)d_in[11];
    const float* w2     = (const float*)d_in[12];
    const float* b2     = (const float*)d_in[13];
    float* out = (float*)d_out;

    char* ws = (char*)d_ws;
    unsigned short* qkvT   = (unsigned short*)(ws);            // [576][192] bf16
    unsigned short* projT  = (unsigned short*)(ws + 221184);   // [192][192] bf16
    unsigned short* w1T    = (unsigned short*)(ws + 294912);   // [384][192] bf16
    unsigned short* w2T    = (unsigned short*)(ws + 442368);   // [192][384] bf16
    unsigned short* biasT4 = (unsigned short*)(ws + 589824);   // [4][6][64][64] bf16 (masked, /ln2)

    k_prep<<<1536, 256, 0, stream>>>(qkv_w, proj_w, w1, w2, relTab, qkvT, projT, w1T, w2T, biasT4);
    k_fused<<<2048, 768, 0, stream>>>(x, n1g, n1b, qkvT, qkv_b, projT, proj_b, biasT4,
                                      n2g, n2b, w1T, b1, w2T, b2, out);
}

// Round 18
// 274.956 us; speedup vs baseline: 1.0219x; 1.0219x over previous
//
#include <hip/hip_runtime.h>
#include <hip/hip_bf16.h>

#define CC 192

typedef __attribute__((ext_vector_type(8))) short bf16x8;
typedef __attribute__((ext_vector_type(4))) float f32x4;

// RNE float->bf16 via the compiler's native cast (lowers to cvt_pk-class ops).
__device__ __forceinline__ unsigned short f2bf(float f) {
    __hip_bfloat16 h = __float2bfloat16(f);
    unsigned short u;
    __builtin_memcpy(&u, &h, 2);
    return u;
}

__device__ __forceinline__ float bf2f(unsigned short u) {
    return __uint_as_float(((unsigned int)u) << 16);
}

// 2^x via native v_exp_f32 (single VALU op).
__device__ __forceinline__ float fast_exp2(float x) {
#if __has_builtin(__builtin_amdgcn_exp2f)
    return __builtin_amdgcn_exp2f(x);
#else
    return __expf(0.69314718055994531f * x);
#endif
}

__device__ __forceinline__ f32x4 mfma16(bf16x8 a, bf16x8 b, f32x4 c) {
    return __builtin_amdgcn_mfma_f32_16x16x32_bf16(a, b, c, 0, 0, 0);
}

// Merged prep: 4 weight transposes (f32 [K][N] -> bf16 [N][K]) + 4-class masked bias table.
// Bias table premultiplied by 1/ln2 so softmax uses native exp2 (no per-score mul).
__global__ void k_prep(const float* __restrict__ qkv_w, const float* __restrict__ proj_w,
                       const float* __restrict__ w1, const float* __restrict__ w2,
                       const float* __restrict__ relTab,
                       unsigned short* __restrict__ qkvT, unsigned short* __restrict__ projT,
                       unsigned short* __restrict__ w1T, unsigned short* __restrict__ w2T,
                       unsigned short* __restrict__ biasT4) {
    int idx = blockIdx.x * blockDim.x + threadIdx.x;
    if (idx < 110592) { int n = idx / 192, k = idx % 192; qkvT[idx] = f2bf(qkv_w[k * 576 + n]); return; }
    idx -= 110592;
    if (idx < 36864)  { int n = idx / 192, k = idx % 192; projT[idx] = f2bf(proj_w[k * 192 + n]); return; }
    idx -= 36864;
    if (idx < 73728)  { int n = idx / 192, k = idx % 192; w1T[idx] = f2bf(w1[k * 384 + n]); return; }
    idx -= 73728;
    if (idx < 73728)  { int n = idx / 384, k = idx % 384; w2T[idx] = f2bf(w2[k * 192 + n]); return; }
    idx -= 73728;
    if (idx < 98304) {   // [cls][h][i][j]: cls = (edgeH?2:0)+(edgeW?1:0); mask pre-added; x 1/ln2
        const int cls = idx / 24576, rem = idx % 24576;
        const int h = rem >> 12, i = (rem >> 6) & 63, j = rem & 63;
        const int yi = i >> 3, xi = i & 7, yj = j >> 3, xj = j & 7;
        const int rel = (yi - yj + 7) * 15 + (xi - xj + 7);
        float v = relTab[rel * 6 + h];
        const int bH = cls >> 1, bW = cls & 1;
        const int idi = (bH ? (yi >= 4 ? 2 : 1) : 0) * 3 + (bW ? (xi >= 4 ? 2 : 1) : 0);
        const int idj = (bH ? (yj >= 4 ? 2 : 1) : 0) * 3 + (bW ? (xj >= 4 ? 2 : 1) : 0);
        if (idi != idj) v -= 100.f;   // exp2(-144+O(1)) flushes to 0: exact mask semantics
        biasT4[idx] = f2bf(v * 1.4426950408889634f);
    }
}

// FUSED Swin block: one window per block (2048 blocks), 12 waves (768 threads).
// vs R16: LDS expanded 74->120 KB (free at 1 block/CU) to DELETE two barriers:
//   - P gets a dedicated 48 KB region (no Q/K overlay) -> bar4 ("Q/K in regs") removed
//   - G is full-width 48 KB (aliases dead P) -> MLP is single-pass, one less barrier
// LDS map: rA [0,24K): A -> VT -> AO -> A2 | rQ [24K,48K): Q -> h-bf16 |
//          rK [48K,72K): K | rP [72K,120K): P [6][64][64] -> G [64][384]
// 8 barriers total (was 10). h in LDS only; `out` written exactly once.
__global__ __launch_bounds__(768, 3) void k_fused(
    const float* __restrict__ x,
    const float* __restrict__ n1g, const float* __restrict__ n1b,
    const unsigned short* __restrict__ qkvT, const float* __restrict__ qkv_b,
    const unsigned short* __restrict__ projT, const float* __restrict__ proj_b,
    const unsigned short* __restrict__ biasT4,
    const float* __restrict__ n2g, const float* __restrict__ n2b,
    const unsigned short* __restrict__ w1T, const float* __restrict__ b1,
    const unsigned short* __restrict__ w2T, const float* __restrict__ b2,
    float* __restrict__ out)
{
    __shared__ __align__(16) char smem[122880];
    __shared__ int sOpos[64];
    char* const rA = smem;
    char* const rQ = smem + 24576;
    char* const rK = smem + 49152;
    char* const rP = smem + 73728;

    const int tid = threadIdx.x;
    const int wid = blockIdx.x;
    const int b = wid >> 6;
    const int win = wid & 63;
    const int wh = win >> 3, ww = win & 7;
    const int lane = tid & 63;
    const int wave = tid >> 6;
    const int lhi = lane >> 4, llo = lane & 15;

    // ---------- Phase 1: LN1 + shifted window gather (512 threads, 8/token) ----------
    if (tid < 512) {
        const int tok = tid >> 3;
        const int ch0 = (tid & 7) * 24;
        const int yi = tok >> 3, xi = tok & 7;
        const int oy = (wh * 8 + yi + 4) & 63;
        const int ox = (ww * 8 + xi + 4) & 63;
        const int base = ((b * 64 + oy) * 64 + ox) * CC;
        if ((tid & 7) == 0) sOpos[tok] = base;
        float v[24];
        float s = 0.f, ss = 0.f;
        #pragma unroll
        for (int i = 0; i < 6; ++i) {
            const float4 f = *(const float4*)(x + base + ch0 + i * 4);
            v[i*4+0]=f.x; v[i*4+1]=f.y; v[i*4+2]=f.z; v[i*4+3]=f.w;
            s  += f.x + f.y + f.z + f.w;
            ss += f.x*f.x + f.y*f.y + f.z*f.z + f.w*f.w;
        }
        s  += __shfl_xor(s, 1);  s  += __shfl_xor(s, 2);  s  += __shfl_xor(s, 4);
        ss += __shfl_xor(ss, 1); ss += __shfl_xor(ss, 2); ss += __shfl_xor(ss, 4);
        const float mean = s * (1.f / 192.f);
        const float rstd = rsqrtf(ss * (1.f / 192.f) - mean * mean + 1e-5f);
        char* aBase = rA + tok * 384;
        const int sw = (tok & 7) << 4;
        #pragma unroll
        for (int i = 0; i < 12; ++i) {
            const int c = ch0 + i * 2;
            const float a0 = (v[i*2+0] - mean) * rstd * n1g[c]   + n1b[c];
            const float a1 = (v[i*2+1] - mean) * rstd * n1g[c+1] + n1b[c+1];
            *(unsigned int*)(aBase + ((c * 2) ^ sw)) =
                (unsigned int)f2bf(a0) | ((unsigned int)f2bf(a1) << 16);
        }
    }
    __syncthreads();   // bar1: A ready

    // ---------- Phase 2: QKV GEMM, wave w -> cols [48w, 48w+48) ----------
    {
        const int cbase = wave * 48;
        f32x4 acc[4][3] = {};
        #pragma unroll
        for (int ks = 0; ks < 6; ++ks) {
            bf16x8 af[4];
            const int kbyte = ks * 64 + lhi * 16;
            #pragma unroll
            for (int m = 0; m < 4; ++m) {
                const int row = m * 16 + llo;
                af[m] = *(const bf16x8*)(rA + row * 384 + (kbyte ^ ((row & 7) << 4)));
            }
            #pragma unroll
            for (int n = 0; n < 3; ++n) {
                const bf16x8 bfr = *(const bf16x8*)(qkvT + (cbase + n * 16 + llo) * 192 + ks * 32 + lhi * 8);
                #pragma unroll
                for (int m = 0; m < 4; ++m) acc[m][n] = mfma16(af[m], bfr, acc[m][n]);
            }
        }
        __syncthreads();   // bar2: A fully consumed; rA region free for VT
        // epilogue: +bias, scatter to Q/K/VT LDS (SCALE*1/ln2 folded into Q for exp2 softmax)
        #pragma unroll
        for (int n = 0; n < 3; ++n) {
            const int c0 = cbase + n * 16;
            const int which = c0 / 192;
            const int rem = c0 - which * 192;
            const int h = rem >> 5;
            const int d = (rem & 31) + llo;
            const float bia = qkv_b[c0 + llo];
            #pragma unroll
            for (int m = 0; m < 4; ++m) {
                #pragma unroll
                for (int r = 0; r < 4; ++r) {
                    const int row = m * 16 + lhi * 4 + r;
                    if (which == 0)
                        *(unsigned short*)(rQ + h * 4096 + row * 64 + ((2 * d) ^ ((row & 3) << 4)))
                            = f2bf((acc[m][n][r] + bia) * 0.2550510257216822f);
                    else if (which == 1)
                        *(unsigned short*)(rK + h * 4096 + row * 64 + ((2 * d) ^ ((row & 3) << 4)))
                            = f2bf(acc[m][n][r] + bia);
                    else
                        *(unsigned short*)(rA + h * 4096 + d * 128 + ((2 * row) ^ ((d & 7) << 4)))
                            = f2bf(acc[m][n][r] + bia);
                }
            }
        }
    }
    __syncthreads();   // bar3: Q/K/VT visible

    // ---------- Phase 3: attention (head = wave>>1, row-half = wave&1) ----------
    // P has a dedicated region (rP) -> no barrier between frag loads and P writes.
    const int h = wave >> 1;
    const int mh = wave & 1;
    f32x4 pacc[2][2] = {};
    float rinv[2][4];
    {
        bf16x8 qf[2], kf[4];
        #pragma unroll
        for (int m = 0; m < 2; ++m) {
            const int t = (mh * 2 + m) * 16 + llo;
            qf[m] = *(const bf16x8*)(rQ + h * 4096 + t * 64 + ((lhi * 16) ^ ((t & 3) << 4)));
        }
        #pragma unroll
        for (int n = 0; n < 4; ++n) {
            const int t = n * 16 + llo;
            kf[n] = *(const bf16x8*)(rK + h * 4096 + t * 64 + ((lhi * 16) ^ ((t & 3) << 4)));
        }

        f32x4 sacc[2][4] = {};
        #pragma unroll
        for (int m = 0; m < 2; ++m)
            #pragma unroll
            for (int n = 0; n < 4; ++n)
                sacc[m][n] = mfma16(qf[m], kf[n], sacc[m][n]);

        // 4-class premasked, pre-1/ln2 bias table: softmax on native exp2, no-max
        const int cls = ((wh == 7) ? 2 : 0) + ((ww == 7) ? 1 : 0);
        const unsigned short* bT = biasT4 + cls * 24576 + h * 4096;
        char* const pBase = rP + h * 8192;
        #pragma unroll
        for (int m = 0; m < 2; ++m) {
            #pragma unroll
            for (int r = 0; r < 4; ++r) {
                const int i = (mh * 2 + m) * 16 + lhi * 4 + r;
                float sum = 0.f;
                unsigned short pb[4];
                #pragma unroll
                for (int n = 0; n < 4; ++n) {
                    const int j = n * 16 + llo;
                    const float e = fast_exp2(sacc[m][n][r] + bf2f(bT[i * 64 + j]));
                    sum += e;
                    pb[n] = f2bf(e);
                }
                sum += __shfl_xor(sum, 1);
                sum += __shfl_xor(sum, 2);
                sum += __shfl_xor(sum, 4);
                sum += __shfl_xor(sum, 8);
                rinv[m][r] = 1.f / sum;
                #pragma unroll
                for (int n = 0; n < 4; ++n) {
                    const int j = n * 16 + llo;
                    *(unsigned short*)(pBase + i * 128 + ((2 * j) ^ ((i & 7) << 4))) = pb[n];
                }
            }
        }
        // P is wave-private (own 32 rows) -> same-wave LDS ordering, no barrier before PV.
        #pragma unroll
        for (int ks = 0; ks < 2; ++ks) {
            bf16x8 pf[2];
            #pragma unroll
            for (int m = 0; m < 2; ++m) {
                const int t = (mh * 2 + m) * 16 + llo;
                pf[m] = *(const bf16x8*)(pBase + t * 128 + ((ks * 64 + lhi * 16) ^ ((t & 7) << 4)));
            }
            #pragma unroll
            for (int n = 0; n < 2; ++n) {
                const int d = n * 16 + llo;
                const bf16x8 vf = *(const bf16x8*)(rA + h * 4096 + d * 128 + ((ks * 64 + lhi * 16) ^ ((d & 7) << 4)));
                #pragma unroll
                for (int m = 0; m < 2; ++m) pacc[m][n] = mfma16(pf[m], vf, pacc[m][n]);
            }
        }
    }
    __syncthreads();   // bar4: all VT reads done; rA free for AO
    {
        #pragma unroll
        for (int m = 0; m < 2; ++m) {
            #pragma unroll
            for (int n = 0; n < 2; ++n) {
                const int c = h * 32 + n * 16 + llo;
                #pragma unroll
                for (int r = 0; r < 4; ++r) {
                    const int i = (mh * 2 + m) * 16 + lhi * 4 + r;
                    *(unsigned short*)(rA + i * 384 + ((c * 2) ^ ((i & 7) << 4)))
                        = f2bf(pacc[m][n][r] * rinv[m][r]);
                }
            }
        }
    }
    __syncthreads();   // bar5: AO ready

    // ---------- Phase 4: proj GEMM + residual -> h (bf16) kept in LDS at rQ ----------
    {
        const int cbase = wave * 16;
        f32x4 acc[4] = {};
        #pragma unroll
        for (int ks = 0; ks < 6; ++ks) {
            bf16x8 af[4];
            const int kbyte = ks * 64 + lhi * 16;
            #pragma unroll
            for (int m = 0; m < 4; ++m) {
                const int row = m * 16 + llo;
                af[m] = *(const bf16x8*)(rA + row * 384 + (kbyte ^ ((row & 7) << 4)));
            }
            const bf16x8 bfr = *(const bf16x8*)(projT + (cbase + llo) * 192 + ks * 32 + lhi * 8);
            #pragma unroll
            for (int m = 0; m < 4; ++m) acc[m] = mfma16(af[m], bfr, acc[m]);
        }
        const int c = cbase + llo;
        const float pb = proj_b[c];
        #pragma unroll
        for (int m = 0; m < 4; ++m) {
            #pragma unroll
            for (int r = 0; r < 4; ++r) {
                const int i = m * 16 + lhi * 4 + r;
                const float hv = x[sOpos[i] + c] + acc[m][r] + pb;
                *(unsigned short*)(rQ + i * 384 + ((2 * c) ^ ((i & 7) << 4))) = f2bf(hv);
            }
        }
    }
    __syncthreads();   // bar6: h-bf16 visible in rQ

    // ---------- Phase 5: LN2 from LDS h -> A2 at rA ----------
    if (tid < 512) {
        const int tok = tid >> 3;
        const int ch0 = (tid & 7) * 24;
        const int sw = (tok & 7) << 4;
        float v[24]; float s = 0.f, ss = 0.f;
        #pragma unroll
        for (int i = 0; i < 12; ++i) {
            const int c = ch0 + i * 2;
            const unsigned uu = *(const unsigned*)(rQ + tok * 384 + ((2 * c) ^ sw));
            const float a0 = bf2f((unsigned short)uu);
            const float a1 = bf2f((unsigned short)(uu >> 16));
            v[2*i] = a0; v[2*i+1] = a1;
            s += a0 + a1;
            ss += a0 * a0 + a1 * a1;
        }
        s  += __shfl_xor(s, 1);  s  += __shfl_xor(s, 2);  s  += __shfl_xor(s, 4);
        ss += __shfl_xor(ss, 1); ss += __shfl_xor(ss, 2); ss += __shfl_xor(ss, 4);
        const float mean = s * (1.f / 192.f);
        const float rstd = rsqrtf(ss * (1.f / 192.f) - mean * mean + 1e-5f);
        char* aBase = rA + tok * 384;
        #pragma unroll
        for (int i = 0; i < 12; ++i) {
            const int c = ch0 + i * 2;
            const float a0 = (v[i*2]   - mean) * rstd * n2g[c]   + n2b[c];
            const float a1 = (v[i*2+1] - mean) * rstd * n2g[c+1] + n2b[c+1];
            *(unsigned int*)(aBase + ((c * 2) ^ sw)) =
                (unsigned int)f2bf(a0) | ((unsigned int)f2bf(a1) << 16);
        }
    }
    __syncthreads();   // bar7: A2 ready; rP (P dead since bar4) free for G

    // ---------- Phase 6: MLP GEMM1 (192->384, single pass) + GELU -> G full at rP ----------
    {
        const int cbase = wave * 32;
        f32x4 a1[4][2] = {};
        #pragma unroll
        for (int ks = 0; ks < 6; ++ks) {
            bf16x8 af[4];
            const int kbyte = ks * 64 + lhi * 16;
            #pragma unroll
            for (int m = 0; m < 4; ++m) {
                const int row = m * 16 + llo;
                af[m] = *(const bf16x8*)(rA + row * 384 + (kbyte ^ ((row & 7) << 4)));
            }
            #pragma unroll
            for (int n = 0; n < 2; ++n) {
                const bf16x8 bfr = *(const bf16x8*)(w1T + (cbase + n * 16 + llo) * 192 + ks * 32 + lhi * 8);
                #pragma unroll
                for (int m = 0; m < 4; ++m) a1[m][n] = mfma16(af[m], bfr, a1[m][n]);
            }
        }
        #pragma unroll
        for (int n = 0; n < 2; ++n) {
            const int c = cbase + n * 16 + llo;
            const float bb = b1[c];
            #pragma unroll
            for (int m = 0; m < 4; ++m) {
                #pragma unroll
                for (int r = 0; r < 4; ++r) {
                    const int i = m * 16 + lhi * 4 + r;
                    const float u = a1[m][n][r] + bb;
                    // gelu_tanh == u / (1 + 2^{-(2k/ln2)(u+0.044715u^3)})
                    const float xx = 2.3022211096534824f * (u + 0.044715f * u * u * u);
                    const float g = u / (1.f + fast_exp2(-xx));
                    *(unsigned short*)(rP + i * 768 + ((2 * c) ^ ((i & 7) << 4))) = f2bf(g);
                }
            }
        }
    }
    __syncthreads();   // bar8: G ready

    // ---------- Phase 7: MLP GEMM2 (384->192) + final residual, single global write ----------
    {
        const int c = wave * 16 + llo;
        f32x4 accM[4] = {};
        #pragma unroll
        for (int ks = 0; ks < 12; ++ks) {
            bf16x8 af[4];
            const int kbyte = ks * 64 + lhi * 16;
            #pragma unroll
            for (int m = 0; m < 4; ++m) {
                const int row = m * 16 + llo;
                af[m] = *(const bf16x8*)(rP + row * 768 + (kbyte ^ ((row & 7) << 4)));
            }
            const bf16x8 bfr = *(const bf16x8*)(w2T + c * 384 + ks * 32 + lhi * 8);
            #pragma unroll
            for (int m = 0; m < 4; ++m) accM[m] = mfma16(af[m], bfr, accM[m]);
        }
        const float bb = b2[c];
        #pragma unroll
        for (int m = 0; m < 4; ++m) {
            #pragma unroll
            for (int r = 0; r < 4; ++r) {
                const int i = m * 16 + lhi * 4 + r;
                const float hv = bf2f(*(const unsigned short*)(rQ + i * 384 + ((2 * c) ^ ((i & 7) << 4))));
                out[sOpos[i] + c] = hv + accM[m][r] + bb;
            }
        }
    }
}

extern "C" void kernel_launch(void* const* d_in, const int* in_sizes, int n_in,
                              void* d_out, int out_size, void* d_ws, size_t ws_size,
                              hipStream_t stream)
{
    const float* x      = (const float*)d_in[0];
    const float* n1g    = (const float*)d_in[1];
    const float* n1b    = (const float*)d_in[2];
    const float* qkv_w  = (const float*)d_in[3];
    const float* qkv_b  = (const float*)d_in[4];
    const float* proj_w = (const float*)d_in[5];
    const float* proj_b = (const float*)d_in[6];
    const float* relTab = (const float*)d_in[7];
    const float* n2g    = (const float*)d_in[8];
    const float* n2b    = (const float*)d_in[9];
    const float* w1     = (const float*)d_in[10];
    const float* b1     = (const float*)d_in[11];
    const float* w2     = (const float*)d_in[12];
    const float* b2     = (const float*)d_in[13];
    float* out = (float*)d_out;

    char* ws = (char*)d_ws;
    unsigned short* qkvT   = (unsigned short*)(ws);            // [576][192] bf16
    unsigned short* projT  = (unsigned short*)(ws + 221184);   // [192][192] bf16
    unsigned short* w1T    = (unsigned short*)(ws + 294912);   // [384][192] bf16
    unsigned short* w2T    = (unsigned short*)(ws + 442368);   // [192][384] bf16
    unsigned short* biasT4 = (unsigned short*)(ws + 589824);   // [4][6][64][64] bf16 (masked, /ln2)

    k_prep<<<1536, 256, 0, stream>>>(qkv_w, proj_w, w1, w2, relTab, qkvT, projT, w1T, w2T, biasT4);
    k_fused<<<2048, 768, 0, stream>>>(x, n1g, n1b, qkvT, qkv_b, projT, proj_b, biasT4,
                                      n2g, n2b, w1T, b1, w2T, b2, out);
}

// Round 19
// 262.006 us; speedup vs baseline: 1.0724x; 1.0494x over previous
//
#include <hip/hip_runtime.h>
#include <hip/hip_bf16.h>

#define CC 192

typedef __attribute__((ext_vector_type(8))) short bf16x8;
typedef __attribute__((ext_vector_type(4))) float f32x4;

// RNE float->bf16 via the compiler's native cast (lowers to cvt_pk-class ops).
__device__ __forceinline__ unsigned short f2bf(float f) {
    __hip_bfloat16 h = __float2bfloat16(f);
    unsigned short u;
    __builtin_memcpy(&u, &h, 2);
    return u;
}

__device__ __forceinline__ float bf2f(unsigned short u) {
    return __uint_as_float(((unsigned int)u) << 16);
}

// 2^x via native v_exp_f32 (single VALU op).
__device__ __forceinline__ float fast_exp2(float x) {
#if __has_builtin(__builtin_amdgcn_exp2f)
    return __builtin_amdgcn_exp2f(x);
#else
    return __expf(0.69314718055994531f * x);
#endif
}

__device__ __forceinline__ f32x4 mfma16(bf16x8 a, bf16x8 b, f32x4 c) {
    return __builtin_amdgcn_mfma_f32_16x16x32_bf16(a, b, c, 0, 0, 0);
}

// Merged prep: 4 weight transposes (f32 [K][N] -> bf16 [N][K]) + 4-class masked bias table.
// Bias table premultiplied by 1/ln2 so softmax uses native exp2 (no per-score mul).
__global__ void k_prep(const float* __restrict__ qkv_w, const float* __restrict__ proj_w,
                       const float* __restrict__ w1, const float* __restrict__ w2,
                       const float* __restrict__ relTab,
                       unsigned short* __restrict__ qkvT, unsigned short* __restrict__ projT,
                       unsigned short* __restrict__ w1T, unsigned short* __restrict__ w2T,
                       unsigned short* __restrict__ biasT4) {
    int idx = blockIdx.x * blockDim.x + threadIdx.x;
    if (idx < 110592) { int n = idx / 192, k = idx % 192; qkvT[idx] = f2bf(qkv_w[k * 576 + n]); return; }
    idx -= 110592;
    if (idx < 36864)  { int n = idx / 192, k = idx % 192; projT[idx] = f2bf(proj_w[k * 192 + n]); return; }
    idx -= 36864;
    if (idx < 73728)  { int n = idx / 192, k = idx % 192; w1T[idx] = f2bf(w1[k * 384 + n]); return; }
    idx -= 73728;
    if (idx < 73728)  { int n = idx / 384, k = idx % 384; w2T[idx] = f2bf(w2[k * 192 + n]); return; }
    idx -= 73728;
    if (idx < 98304) {   // [cls][h][i][j]: cls = (edgeH?2:0)+(edgeW?1:0); mask pre-added; x 1/ln2
        const int cls = idx / 24576, rem = idx % 24576;
        const int h = rem >> 12, i = (rem >> 6) & 63, j = rem & 63;
        const int yi = i >> 3, xi = i & 7, yj = j >> 3, xj = j & 7;
        const int rel = (yi - yj + 7) * 15 + (xi - xj + 7);
        float v = relTab[rel * 6 + h];
        const int bH = cls >> 1, bW = cls & 1;
        const int idi = (bH ? (yi >= 4 ? 2 : 1) : 0) * 3 + (bW ? (xi >= 4 ? 2 : 1) : 0);
        const int idj = (bH ? (yj >= 4 ? 2 : 1) : 0) * 3 + (bW ? (xj >= 4 ? 2 : 1) : 0);
        if (idi != idj) v -= 100.f;   // exp2(-144+O(1)) flushes to 0: exact mask semantics
        biasT4[idx] = f2bf(v * 1.4426950408889634f);
    }
}

// FUSED Swin block: TWO windows per block (1024 blocks), 12 waves (768 threads), 144.5 KB LDS.
// Rationale: 1 block/CU regardless (occupancy ledger closed R5-R13), so LDS to 144 KB is free.
// 2x work per phase halves per-window barrier density AND shares every GEMM B-panel across
// both windows. Attention: wave = (window v, head h) slot, full head, two 32-row halves
// (keeps every program point's live set ~<=140 regs; budget 170 at (768,3)).
// LDS map (t = v*64+tok is the global row, 0..127):
//   rA [0,48K):    A [128][192]swz -> VT 12 slots x 4K -> AO [128][192] -> A2
//   rQ [48K,96K):  Q 12 slots x 4K -> P slots 0-5 (8K each, spans into rK) -> h-bf16 [128][192]
//   rK [96K,144K): K 12 slots x 4K -> P slots 6-11 -> G-half [128][192] (MLP two-pass)
__global__ __launch_bounds__(768, 3) void k_fused(
    const float* __restrict__ x,
    const float* __restrict__ n1g, const float* __restrict__ n1b,
    const unsigned short* __restrict__ qkvT, const float* __restrict__ qkv_b,
    const unsigned short* __restrict__ projT, const float* __restrict__ proj_b,
    const unsigned short* __restrict__ biasT4,
    const float* __restrict__ n2g, const float* __restrict__ n2b,
    const unsigned short* __restrict__ w1T, const float* __restrict__ b1,
    const unsigned short* __restrict__ w2T, const float* __restrict__ b2,
    float* __restrict__ out)
{
    __shared__ __align__(16) char smem[147456];
    __shared__ int sOpos[128];
    char* const rA = smem;
    char* const rQ = smem + 49152;
    char* const rK = smem + 98304;

    const int tid = threadIdx.x;
    const int wid = blockIdx.x;
    const int lane = tid & 63;
    const int wave = tid >> 6;
    const int lhi = lane >> 4, llo = lane & 15;

    // ---------- Phase 1: LN1 + shifted window gather, 128 tokens in 96+32 chunks ----------
    auto ln1_token = [&](int t) {
        const int v = t >> 6;
        const int gwin = wid * 2 + v;
        const int bb_ = gwin >> 6;
        const int win_ = gwin & 63;
        const int tok = t & 63;
        const int oy = ((win_ >> 3) * 8 + (tok >> 3) + 4) & 63;
        const int ox = ((win_ & 7) * 8 + (tok & 7) + 4) & 63;
        const int base = ((bb_ * 64 + oy) * 64 + ox) * CC;
        const int ch0 = (tid & 7) * 24;
        if ((tid & 7) == 0) sOpos[t] = base;
        float vv[24];
        float s = 0.f, ss = 0.f;
        #pragma unroll
        for (int i = 0; i < 6; ++i) {
            const float4 f = *(const float4*)(x + base + ch0 + i * 4);
            vv[i*4+0]=f.x; vv[i*4+1]=f.y; vv[i*4+2]=f.z; vv[i*4+3]=f.w;
            s  += f.x + f.y + f.z + f.w;
            ss += f.x*f.x + f.y*f.y + f.z*f.z + f.w*f.w;
        }
        s  += __shfl_xor(s, 1);  s  += __shfl_xor(s, 2);  s  += __shfl_xor(s, 4);
        ss += __shfl_xor(ss, 1); ss += __shfl_xor(ss, 2); ss += __shfl_xor(ss, 4);
        const float mean = s * (1.f / 192.f);
        const float rstd = rsqrtf(ss * (1.f / 192.f) - mean * mean + 1e-5f);
        char* aBase = rA + t * 384;
        const int sw = (t & 7) << 4;
        #pragma unroll
        for (int i = 0; i < 12; ++i) {
            const int c = ch0 + i * 2;
            const float a0 = (vv[i*2+0] - mean) * rstd * n1g[c]   + n1b[c];
            const float a1 = (vv[i*2+1] - mean) * rstd * n1g[c+1] + n1b[c+1];
            *(unsigned int*)(aBase + ((c * 2) ^ sw)) =
                (unsigned int)f2bf(a0) | ((unsigned int)f2bf(a1) << 16);
        }
    };
    ln1_token(tid >> 3);                       // tokens 0..95
    if (tid < 256) ln1_token(96 + (tid >> 3)); // tokens 96..127
    __syncthreads();   // bar1: A ready

    // ---------- Phase 2: QKV GEMM, wave w -> cols [48w,+48) for BOTH windows ----------
    {
        const int cbase = wave * 48;
        f32x4 acc[2][4][3] = {};
        #pragma unroll
        for (int ks = 0; ks < 6; ++ks) {
            const int kbyte = ks * 64 + lhi * 16;
            bf16x8 bfr[3];
            #pragma unroll
            for (int n = 0; n < 3; ++n)
                bfr[n] = *(const bf16x8*)(qkvT + (cbase + n * 16 + llo) * 192 + ks * 32 + lhi * 8);
            #pragma unroll
            for (int v = 0; v < 2; ++v) {
                bf16x8 af[4];
                #pragma unroll
                for (int m = 0; m < 4; ++m) {
                    const int row = v * 64 + m * 16 + llo;
                    af[m] = *(const bf16x8*)(rA + row * 384 + (kbyte ^ ((row & 7) << 4)));
                }
                #pragma unroll
                for (int n = 0; n < 3; ++n)
                    #pragma unroll
                    for (int m = 0; m < 4; ++m)
                        acc[v][m][n] = mfma16(af[m], bfr[n], acc[v][m][n]);
            }
        }
        __syncthreads();   // bar2: A fully consumed; rA free for VT
        // epilogue: +bias, scatter to Q/K/VT (SCALE*1/ln2 folded into Q)
        #pragma unroll
        for (int v = 0; v < 2; ++v) {
            #pragma unroll
            for (int n = 0; n < 3; ++n) {
                const int c0 = cbase + n * 16;
                const int which = c0 / 192;
                const int rem = c0 - which * 192;
                const int hs = v * 6 + (rem >> 5);
                const int d = (rem & 31) + llo;
                const float bia = qkv_b[c0 + llo];
                #pragma unroll
                for (int m = 0; m < 4; ++m) {
                    #pragma unroll
                    for (int r = 0; r < 4; ++r) {
                        const int row = m * 16 + lhi * 4 + r;
                        if (which == 0)
                            *(unsigned short*)(rQ + hs * 4096 + row * 64 + ((2 * d) ^ ((row & 3) << 4)))
                                = f2bf((acc[v][m][n][r] + bia) * 0.2550510257216822f);
                        else if (which == 1)
                            *(unsigned short*)(rK + hs * 4096 + row * 64 + ((2 * d) ^ ((row & 3) << 4)))
                                = f2bf(acc[v][m][n][r] + bia);
                        else
                            *(unsigned short*)(rA + hs * 4096 + d * 128 + ((2 * row) ^ ((d & 7) << 4)))
                                = f2bf(acc[v][m][n][r] + bia);
                    }
                }
            }
        }
    }
    __syncthreads();   // bar3: Q/K/VT visible

    // ---------- Phase 3: attention — wave = (v,h) slot, full head, two 32-row halves ----------
    const int v = wave / 6;
    const int h = wave - v * 6;
    const int hs = wave;
    f32x4 pacc[2][2][2] = {};
    float rinv[2][2][4];
    {
        bf16x8 qf[4], kf[4];
        #pragma unroll
        for (int m = 0; m < 4; ++m) {
            const int t = m * 16 + llo;
            qf[m] = *(const bf16x8*)(rQ + hs * 4096 + t * 64 + ((lhi * 16) ^ ((t & 3) << 4)));
        }
        #pragma unroll
        for (int n = 0; n < 4; ++n) {
            const int t = n * 16 + llo;
            kf[n] = *(const bf16x8*)(rK + hs * 4096 + t * 64 + ((lhi * 16) ^ ((t & 3) << 4)));
        }
        __syncthreads();   // bar4: Q/K in regs everywhere; rQ+rK free for P

        const int win_ = (wid * 2 + v) & 63;
        const int cls = (((win_ >> 3) == 7) ? 2 : 0) + (((win_ & 7) == 7) ? 1 : 0);
        const unsigned short* bT = biasT4 + cls * 24576 + h * 4096;
        char* const pBase = rQ + hs * 8192;
        #pragma unroll
        for (int hh = 0; hh < 2; ++hh) {
            f32x4 sacc[2][4] = {};
            #pragma unroll
            for (int m = 0; m < 2; ++m)
                #pragma unroll
                for (int n = 0; n < 4; ++n)
                    sacc[m][n] = mfma16(qf[hh * 2 + m], kf[n], sacc[m][n]);
            // no-max softmax on native exp2; P = unnormalized e
            #pragma unroll
            for (int m = 0; m < 2; ++m) {
                #pragma unroll
                for (int r = 0; r < 4; ++r) {
                    const int i = (hh * 2 + m) * 16 + lhi * 4 + r;
                    float sum = 0.f;
                    unsigned short pb[4];
                    #pragma unroll
                    for (int n = 0; n < 4; ++n) {
                        const int j = n * 16 + llo;
                        const float e = fast_exp2(sacc[m][n][r] + bf2f(bT[i * 64 + j]));
                        sum += e;
                        pb[n] = f2bf(e);
                    }
                    sum += __shfl_xor(sum, 1);
                    sum += __shfl_xor(sum, 2);
                    sum += __shfl_xor(sum, 4);
                    sum += __shfl_xor(sum, 8);
                    rinv[hh][m][r] = 1.f / sum;
                    #pragma unroll
                    for (int n = 0; n < 4; ++n) {
                        const int j = n * 16 + llo;
                        *(unsigned short*)(pBase + i * 128 + ((2 * j) ^ ((i & 7) << 4))) = pb[n];
                    }
                }
            }
            // PV for this half (wave-private P rows -> same-wave ordering, no barrier)
            #pragma unroll
            for (int ks = 0; ks < 2; ++ks) {
                bf16x8 pf[2];
                #pragma unroll
                for (int m = 0; m < 2; ++m) {
                    const int t = (hh * 2 + m) * 16 + llo;
                    pf[m] = *(const bf16x8*)(pBase + t * 128 + ((ks * 64 + lhi * 16) ^ ((t & 7) << 4)));
                }
                #pragma unroll
                for (int n = 0; n < 2; ++n) {
                    const int d = n * 16 + llo;
                    const bf16x8 vf = *(const bf16x8*)(rA + hs * 4096 + d * 128 + ((ks * 64 + lhi * 16) ^ ((d & 7) << 4)));
                    #pragma unroll
                    for (int m = 0; m < 2; ++m) pacc[hh][m][n] = mfma16(pf[m], vf, pacc[hh][m][n]);
                }
            }
        }
    }
    __syncthreads();   // bar5: all VT/P reads done; rA free for AO
    {
        #pragma unroll
        for (int hh = 0; hh < 2; ++hh) {
            #pragma unroll
            for (int m = 0; m < 2; ++m) {
                #pragma unroll
                for (int n = 0; n < 2; ++n) {
                    const int c = h * 32 + n * 16 + llo;
                    #pragma unroll
                    for (int r = 0; r < 4; ++r) {
                        const int t = v * 64 + (hh * 2 + m) * 16 + lhi * 4 + r;
                        *(unsigned short*)(rA + t * 384 + ((c * 2) ^ ((t & 7) << 4)))
                            = f2bf(pacc[hh][m][n][r] * rinv[hh][m][r]);
                    }
                }
            }
        }
    }
    __syncthreads();   // bar6: AO ready

    // ---------- Phase 4: proj GEMM + residual -> h (bf16) in rQ; wave -> cols [16w,+16), 128 rows ----------
    {
        const int c = wave * 16 + llo;
        f32x4 acc[8] = {};
        #pragma unroll
        for (int ks = 0; ks < 6; ++ks) {
            const int kbyte = ks * 64 + lhi * 16;
            const bf16x8 bfr = *(const bf16x8*)(projT + c * 192 + ks * 32 + lhi * 8);
            #pragma unroll
            for (int m = 0; m < 8; ++m) {
                const int row = m * 16 + llo;
                const bf16x8 af = *(const bf16x8*)(rA + row * 384 + (kbyte ^ ((row & 7) << 4)));
                acc[m] = mfma16(af, bfr, acc[m]);
            }
        }
        const float pb = proj_b[c];
        #pragma unroll
        for (int m = 0; m < 8; ++m) {
            #pragma unroll
            for (int r = 0; r < 4; ++r) {
                const int t = m * 16 + lhi * 4 + r;
                const float hv = x[sOpos[t] + c] + acc[m][r] + pb;
                *(unsigned short*)(rQ + t * 384 + ((2 * c) ^ ((t & 7) << 4))) = f2bf(hv);
            }
        }
    }
    __syncthreads();   // bar7: h-bf16 visible in rQ

    // ---------- Phase 5: LN2 from LDS h -> A2 at rA, 128 tokens in 96+32 chunks ----------
    auto ln2_token = [&](int t) {
        const int ch0 = (tid & 7) * 24;
        const int sw = (t & 7) << 4;
        float vv[24]; float s = 0.f, ss = 0.f;
        #pragma unroll
        for (int i = 0; i < 12; ++i) {
            const int c = ch0 + i * 2;
            const unsigned uu = *(const unsigned*)(rQ + t * 384 + ((2 * c) ^ sw));
            const float a0 = bf2f((unsigned short)uu);
            const float a1 = bf2f((unsigned short)(uu >> 16));
            vv[2*i] = a0; vv[2*i+1] = a1;
            s += a0 + a1;
            ss += a0 * a0 + a1 * a1;
        }
        s  += __shfl_xor(s, 1);  s  += __shfl_xor(s, 2);  s  += __shfl_xor(s, 4);
        ss += __shfl_xor(ss, 1); ss += __shfl_xor(ss, 2); ss += __shfl_xor(ss, 4);
        const float mean = s * (1.f / 192.f);
        const float rstd = rsqrtf(ss * (1.f / 192.f) - mean * mean + 1e-5f);
        char* aBase = rA + t * 384;
        #pragma unroll
        for (int i = 0; i < 12; ++i) {
            const int c = ch0 + i * 2;
            const float a0 = (vv[i*2]   - mean) * rstd * n2g[c]   + n2b[c];
            const float a1 = (vv[i*2+1] - mean) * rstd * n2g[c+1] + n2b[c+1];
            *(unsigned int*)(aBase + ((c * 2) ^ sw)) =
                (unsigned int)f2bf(a0) | ((unsigned int)f2bf(a1) << 16);
        }
    };
    ln2_token(tid >> 3);
    if (tid < 256) ln2_token(96 + (tid >> 3));
    __syncthreads();   // bar8: A2 ready; rK (P dead since bar5) free for G-half

    // ---------- Phase 6: MLP in two hidden halves; G-half [128][192] at rK ----------
    f32x4 accM[8] = {};
    #pragma unroll
    for (int hh = 0; hh < 2; ++hh) {
        {
            const int cl = wave * 16 + llo;
            f32x4 a1[8] = {};
            #pragma unroll
            for (int ks = 0; ks < 6; ++ks) {
                const int kbyte = ks * 64 + lhi * 16;
                const bf16x8 bfr = *(const bf16x8*)(w1T + (hh * 192 + cl) * 192 + ks * 32 + lhi * 8);
                #pragma unroll
                for (int m = 0; m < 8; ++m) {
                    const int row = m * 16 + llo;
                    const bf16x8 af = *(const bf16x8*)(rA + row * 384 + (kbyte ^ ((row & 7) << 4)));
                    a1[m] = mfma16(af, bfr, a1[m]);
                }
            }
            const float bb = b1[hh * 192 + cl];
            #pragma unroll
            for (int m = 0; m < 8; ++m) {
                #pragma unroll
                for (int r = 0; r < 4; ++r) {
                    const int t = m * 16 + lhi * 4 + r;
                    const float u = a1[m][r] + bb;
                    // gelu_tanh == u / (1 + 2^{-(2k/ln2)(u+0.044715u^3)})
                    const float xx = 2.3022211096534824f * (u + 0.044715f * u * u * u);
                    const float g = u / (1.f + fast_exp2(-xx));
                    *(unsigned short*)(rK + t * 384 + ((2 * cl) ^ ((t & 7) << 4))) = f2bf(g);
                }
            }
        }
        __syncthreads();   // G-half ready
        {
            const int c = wave * 16 + llo;
            #pragma unroll
            for (int ks = 0; ks < 6; ++ks) {
                const int kbyte = ks * 64 + lhi * 16;
                const bf16x8 bfr = *(const bf16x8*)(w2T + c * 384 + hh * 192 + ks * 32 + lhi * 8);
                #pragma unroll
                for (int m = 0; m < 8; ++m) {
                    const int row = m * 16 + llo;
                    const bf16x8 af = *(const bf16x8*)(rK + row * 384 + (kbyte ^ ((row & 7) << 4)));
                    accM[m] = mfma16(af, bfr, accM[m]);
                }
            }
        }
        if (hh == 0) __syncthreads();   // G-half0 consumed
    }
    // ---------- final: out = h + mlp (single global write) ----------
    {
        const int c = wave * 16 + llo;
        const float bb = b2[c];
        #pragma unroll
        for (int m = 0; m < 8; ++m) {
            #pragma unroll
            for (int r = 0; r < 4; ++r) {
                const int t = m * 16 + lhi * 4 + r;
                const float hv = bf2f(*(const unsigned short*)(rQ + t * 384 + ((2 * c) ^ ((t & 7) << 4))));
                out[sOpos[t] + c] = hv + accM[m][r] + bb;
            }
        }
    }
}

extern "C" void kernel_launch(void* const* d_in, const int* in_sizes, int n_in,
                              void* d_out, int out_size, void* d_ws, size_t ws_size,
                              hipStream_t stream)
{
    const float* x      = (const float*)d_in[0];
    const float* n1g    = (const float*)d_in[1];
    const float* n1b    = (const float*)d_in[2];
    const float* qkv_w  = (const float*)d_in[3];
    const float* qkv_b  = (const float*)d_in[4];
    const float* proj_w = (const float*)d_in[5];
    const float* proj_b = (const float*)d_in[6];
    const float* relTab = (const float*)d_in[7];
    const float* n2g    = (const float*)d_in[8];
    const float* n2b    = (const float*)d_in[9];
    const float* w1     = (const float*)d_in[10];
    const float* b1     = (const float*)d_in[11];
    const float* w2     = (const float*)d_in[12];
    const float* b2     = (const float*)d_in[13];
    float* out = (float*)d_out;

    char* ws = (char*)d_ws;
    unsigned short* qkvT   = (unsigned short*)(ws);            // [576][192] bf16
    unsigned short* projT  = (unsigned short*)(ws + 221184);   // [192][192] bf16
    unsigned short* w1T    = (unsigned short*)(ws + 294912);   // [384][192] bf16
    unsigned short* w2T    = (unsigned short*)(ws + 442368);   // [192][384] bf16
    unsigned short* biasT4 = (unsigned short*)(ws + 589824);   // [4][6][64][64] bf16 (masked, /ln2)

    k_prep<<<1536, 256, 0, stream>>>(qkv_w, proj_w, w1, w2, relTab, qkvT, projT, w1T, w2T, biasT4);
    k_fused<<<1024, 768, 0, stream>>>(x, n1g, n1b, qkvT, qkv_b, projT, proj_b, biasT4,
                                      n2g, n2b, w1T, b1, w2T, b2, out);
}